// Round 1
// 940.069 us; speedup vs baseline: 1.0267x; 1.0267x over previous
//
#include <hip/hip_runtime.h>
#include <hip/hip_bf16.h>
#include <math.h>

typedef unsigned short ushort_t;
typedef __attribute__((ext_vector_type(8))) short bfrag_t;   // 8 bf16 = 4 VGPRs
typedef __attribute__((ext_vector_type(4))) float facc_t;    // 4 f32 acc

#define D_MODEL 512
#define NH 8
#define DH 64
#define NL 6
#define BB 4
#define SS 1024
#define ROWS (BB*SS)   // 4096
#define DFF 2048

__device__ inline ushort_t f2bf(float f) {
    __hip_bfloat16 h = __float2bfloat16(f);
    return *(ushort_t*)&h;
}
__device__ inline void gload_lds16(const void* g, void* l) {
    __builtin_amdgcn_global_load_lds((const __attribute__((address_space(1))) unsigned int*)g,
                                     (__attribute__((address_space(3))) unsigned int*)l, 16, 0, 0);
}

// ---------------------------------------------------------------------------
// Embedding + positional encoding -> x (f32) and xbf (bf16)
// ---------------------------------------------------------------------------
__global__ __launch_bounds__(256) void embed_pe(const int* __restrict__ tok,
                                                const float* __restrict__ emb,
                                                float* __restrict__ x,
                                                ushort_t* __restrict__ xbf) {
    int row = blockIdx.x;
    int s = row & (SS - 1);
    int t = tok[row];
    const float* e = emb + (size_t)t * D_MODEL;
    for (int i = threadIdx.x; i < D_MODEL; i += 256) {
        float freq = __expf(-9.210340371976184f * ((float)i / (float)D_MODEL));
        float ang = (float)s * freq;
        float pe = (i & 1) ? cosf(ang) : sinf(ang);
        float v = e[i] + pe;
        x[(size_t)row * D_MODEL + i] = v;
        xbf[(size_t)row * D_MODEL + i] = f2bf(v);
    }
}

// ---------------------------------------------------------------------------
// Per-layer weight prep: cast f32 -> bf16 and transpose [K][N] -> [N][K].
// ---------------------------------------------------------------------------
__global__ __launch_bounds__(256) void prep_weights(const float* __restrict__ Wq,
                                                    const float* __restrict__ Wk,
                                                    const float* __restrict__ Wv,
                                                    const float* __restrict__ Wo,
                                                    const float* __restrict__ W1,
                                                    const float* __restrict__ W2,
                                                    int layer, ushort_t* __restrict__ wlay) {
    __shared__ float tile[32][33];
    int z = blockIdx.z;
    const float* src; ushort_t* dst; int K, N;
    size_t o512 = (size_t)layer * 512 * 512;
    size_t o1M  = (size_t)layer * 512 * 2048;
    switch (z) {
        case 0: src = Wq + o512; dst = wlay;               K = 512;  N = 512;  break;
        case 1: src = Wk + o512; dst = wlay + 262144;      K = 512;  N = 512;  break;
        case 2: src = Wv + o512; dst = wlay + 524288;      K = 512;  N = 512;  break;
        case 3: src = Wo + o512; dst = wlay + 786432;      K = 512;  N = 512;  break;
        case 4: src = W1 + o1M;  dst = wlay + 1048576;     K = 512;  N = 2048; break;
        default:src = W2 + o1M;  dst = wlay + 2097152;     K = 2048; N = 512;  break;
    }
    int n0 = blockIdx.x * 32, k0 = blockIdx.y * 32;
    if (n0 >= N || k0 >= K) return;
    int tx = threadIdx.x & 31, ty = threadIdx.x >> 5;
    #pragma unroll
    for (int i = 0; i < 4; i++)
        tile[ty + i * 8][tx] = src[(size_t)(k0 + ty + i * 8) * N + n0 + tx];
    __syncthreads();
    #pragma unroll
    for (int i = 0; i < 4; i++)
        dst[(size_t)(n0 + ty + i * 8) * K + k0 + tx] = f2bf(tile[tx][ty + i * 8]);
}

// ---------------------------------------------------------------------------
// Concatenate qkv biases per layer: bqkv[l][1536] = [bq | bk | bv]
// ---------------------------------------------------------------------------
__global__ __launch_bounds__(256) void concat_bias(const float* __restrict__ bq,
                                                   const float* __restrict__ bk,
                                                   const float* __restrict__ bv,
                                                   float* __restrict__ bqkv) {
    int l = blockIdx.x;
    for (int i = threadIdx.x; i < 1536; i += 256) {
        float v = (i < 512) ? bq[l * 512 + i]
                : (i < 1024) ? bk[l * 512 + i - 512]
                : bv[l * 512 + i - 1024];
        bqkv[l * 1536 + i] = v;
    }
}

// ---------------------------------------------------------------------------
// MFMA bf16 GEMM, 128x128 tile / 256 threads, BK=64. For large-N outputs.
// ---------------------------------------------------------------------------
__global__ __launch_bounds__(256) void gemm_mfma(const ushort_t* __restrict__ A,
                                                 const ushort_t* __restrict__ Bt,
                                                 const float* __restrict__ bias,
                                                 float* __restrict__ Cf,
                                                 ushort_t* __restrict__ Cb,
                                                 int N, int K, int relu) {
    __shared__ ushort_t lA[128 * 64];
    __shared__ ushort_t lB[128 * 64];

    const int tid = threadIdx.x;
    const int w = tid >> 6, lane = tid & 63;
    const int wr = w & 1, wc = w >> 1;
    const int lane16 = lane & 15, quad = lane >> 4;
    const int row0 = blockIdx.y * 128, col0 = blockIdx.x * 128;

    facc_t acc[4][4];
    #pragma unroll
    for (int i = 0; i < 4; i++)
        #pragma unroll
        for (int j = 0; j < 4; j++)
            acc[i][j] = (facc_t){0.f, 0.f, 0.f, 0.f};

    for (int k0 = 0; k0 < K; k0 += 64) {
        __syncthreads();
        #pragma unroll
        for (int i = 0; i < 4; i++) {
            int g = w * 256 + i * 64 + lane;
            int r = g >> 3, p = g & 7;
            int q = p ^ (r & 7);
            gload_lds16(A + (size_t)(row0 + r) * K + k0 + q * 8, lA + (size_t)g * 8);
            gload_lds16(Bt + (size_t)(col0 + r) * K + k0 + q * 8, lB + (size_t)g * 8);
        }
        __syncthreads();

        #pragma unroll
        for (int kk = 0; kk < 2; kk++) {
            bfrag_t af[4], bfg[4];
            #pragma unroll
            for (int t = 0; t < 4; t++) {
                int m = wr * 64 + t * 16 + lane16;
                int q = kk * 4 + quad;
                af[t] = *(const bfrag_t*)(lA + ((size_t)m * 8 + (q ^ (m & 7))) * 8);
                int n = wc * 64 + t * 16 + lane16;
                bfg[t] = *(const bfrag_t*)(lB + ((size_t)n * 8 + (q ^ (n & 7))) * 8);
            }
            #pragma unroll
            for (int ti = 0; ti < 4; ti++)
                #pragma unroll
                for (int tj = 0; tj < 4; tj++)
                    acc[ti][tj] = __builtin_amdgcn_mfma_f32_16x16x32_bf16(
                        af[ti], bfg[tj], acc[ti][tj], 0, 0, 0);
        }
    }

    float bv_[4];
    #pragma unroll
    for (int tj = 0; tj < 4; tj++)
        bv_[tj] = bias[col0 + wc * 64 + tj * 16 + lane16];

    #pragma unroll
    for (int ti = 0; ti < 4; ti++) {
        int grow_base = row0 + wr * 64 + ti * 16 + quad * 4;
        #pragma unroll
        for (int tj = 0; tj < 4; tj++) {
            int gcol = col0 + wc * 64 + tj * 16 + lane16;
            #pragma unroll
            for (int rr = 0; rr < 4; rr++) {
                float v = acc[ti][tj][rr] + bv_[tj];
                if (relu) v = fmaxf(v, 0.f);
                size_t idx = (size_t)(grow_base + rr) * N + gcol;
                if (Cf) Cf[idx] = v;
                if (Cb) Cb[idx] = f2bf(v);
            }
        }
    }
}

// ---------------------------------------------------------------------------
// MFMA bf16 GEMM, 64x64 tile / 256 threads, BK=64. For N=512 outputs (Wo/W2):
// grid (N/64=8, M/64=64) = 512 blocks -> 2/CU vs 128-tile's 0.5/CU.
// Wave w covers 32x32 quadrant (wr=w&1 rows, wc=w>>1 cols), 2x2 frags.
// ---------------------------------------------------------------------------
__global__ __launch_bounds__(256) void gemm_mfma64(const ushort_t* __restrict__ A,
                                                   const ushort_t* __restrict__ Bt,
                                                   const float* __restrict__ bias,
                                                   float* __restrict__ Cf,
                                                   ushort_t* __restrict__ Cb,
                                                   int N, int K, int relu) {
    __shared__ ushort_t lA[64 * 64];
    __shared__ ushort_t lB[64 * 64];

    const int tid = threadIdx.x;
    const int w = tid >> 6, lane = tid & 63;
    const int wr = w & 1, wc = w >> 1;
    const int lane16 = lane & 15, quad = lane >> 4;
    const int row0 = blockIdx.y * 64, col0 = blockIdx.x * 64;

    facc_t acc[2][2];
    #pragma unroll
    for (int i = 0; i < 2; i++)
        #pragma unroll
        for (int j = 0; j < 2; j++)
            acc[i][j] = (facc_t){0.f, 0.f, 0.f, 0.f};

    for (int k0 = 0; k0 < K; k0 += 64) {
        __syncthreads();
        // A: 512 granules, B: 512 granules; 4 waves x 128
        #pragma unroll
        for (int i = 0; i < 2; i++) {
            int g = w * 128 + i * 64 + lane;
            int r = g >> 3, p = g & 7;
            int q = p ^ (r & 7);
            gload_lds16(A + (size_t)(row0 + r) * K + k0 + q * 8, lA + (size_t)g * 8);
            gload_lds16(Bt + (size_t)(col0 + r) * K + k0 + q * 8, lB + (size_t)g * 8);
        }
        __syncthreads();

        #pragma unroll
        for (int kk = 0; kk < 2; kk++) {
            bfrag_t af[2], bfg[2];
            #pragma unroll
            for (int t = 0; t < 2; t++) {
                int m = wr * 32 + t * 16 + lane16;
                int q = kk * 4 + quad;
                af[t] = *(const bfrag_t*)(lA + ((size_t)m * 8 + (q ^ (m & 7))) * 8);
                int n = wc * 32 + t * 16 + lane16;
                bfg[t] = *(const bfrag_t*)(lB + ((size_t)n * 8 + (q ^ (n & 7))) * 8);
            }
            #pragma unroll
            for (int ti = 0; ti < 2; ti++)
                #pragma unroll
                for (int tj = 0; tj < 2; tj++)
                    acc[ti][tj] = __builtin_amdgcn_mfma_f32_16x16x32_bf16(
                        af[ti], bfg[tj], acc[ti][tj], 0, 0, 0);
        }
    }

    float bv_[2];
    #pragma unroll
    for (int tj = 0; tj < 2; tj++)
        bv_[tj] = bias[col0 + wc * 32 + tj * 16 + lane16];

    #pragma unroll
    for (int ti = 0; ti < 2; ti++) {
        int grow_base = row0 + wr * 32 + ti * 16 + quad * 4;
        #pragma unroll
        for (int tj = 0; tj < 2; tj++) {
            int gcol = col0 + wc * 32 + tj * 16 + lane16;
            #pragma unroll
            for (int rr = 0; rr < 4; rr++) {
                float v = acc[ti][tj][rr] + bv_[tj];
                if (relu) v = fmaxf(v, 0.f);
                size_t idx = (size_t)(grow_base + rr) * N + gcol;
                if (Cf) Cf[idx] = v;
                if (Cb) Cb[idx] = f2bf(v);
            }
        }
    }
}

// ---------------------------------------------------------------------------
// MFMA flash attention. 128 threads = 2 waves; 32 q-rows/block; grid
// (32 qtiles, NH, BB) = 1024 blocks (4/CU). Wave w owns a 16-row Q strip.
//
// Round-6 changes (latency-bound fix; MfmaUtil was 6%, VALUBusy 27%, 85% of
// each tile was stall):
//  - K/V LDS double-buffered (20KB -> 36KB, still 4 blocks/CU): stage tile
//    t+1 (async K DMA + V reg loads) BEFORE computing tile t, V^T ds_writes
//    after compute, single __syncthreads per iter -> global latency hidden
//    under ~1000cy of compute instead of exposed at a drain barrier.
//  - exp2-domain softmax: p = exp2(fma(s, 0.125*log2e, -m*log2e)) = fma+exp
//    (2 ops) vs mul+sub+mul+exp (4 ops), 16x per thread per tile.
//  - defer-rescale (THR=8): skip alpha-exp + 16 O-mults when
//    __all(mt - m <= 8); P bounded by e^8, exact after final O/l normalize.
// ---------------------------------------------------------------------------
__global__ __launch_bounds__(128) void attn_mfma(const ushort_t* __restrict__ qkv,
                                                 ushort_t* __restrict__ ab) {
    __shared__ __align__(16) ushort_t lK[2][4096];   // [64 key][64 dh] swizzled
    __shared__ __align__(16) ushort_t lVT[2][4096];  // [64 dh][64 key] swizzled
    __shared__ __align__(16) ushort_t lP[2048];      // 2 x [16 q][64 key] swizzled

    const int tid = threadIdx.x;
    const int w = tid >> 6, lane = tid & 63;
    const int lane16 = lane & 15, quad = lane >> 4;
    const int qt = blockIdx.x, h = blockIdx.y, b = blockIdx.z;

    // Q A-fragments for this wave's 16 rows (regs for entire loop)
    const ushort_t* Qrow = qkv + (size_t)(b * SS + qt * 32 + w * 16 + lane16) * 1536 + h * 64;
    bfrag_t qa[2];
    #pragma unroll
    for (int ks = 0; ks < 2; ks++)
        qa[ks] = *(const bfrag_t*)(Qrow + ks * 32 + quad * 8);

    facc_t O[4];
    #pragma unroll
    for (int t = 0; t < 4; t++) O[t] = (facc_t){0.f, 0.f, 0.f, 0.f};
    float mrow[4] = {-INFINITY, -INFINITY, -INFINITY, -INFINITY};
    float lrow[4] = {0.f, 0.f, 0.f, 0.f};

    const int vkey = tid & 63;   // V^T staging: thread -> (key, dh half)
    const int vdg  = tid >> 6;   // 0 or 1 -> dh in [vdg*32, vdg*32+32)
    const int vk8 = vkey >> 3, vj = vkey & 7;

    const float LOG2E = 1.4426950408889634f;
    const float SC = 0.125f * 1.4426950408889634f;   // score scale folded into log2e

    auto stageK = [&](int kt, int buf) {
        #pragma unroll
        for (int i = 0; i < 4; i++) {
            int g = i * 128 + tid;
            int r = g >> 3, p = g & 7;
            int q = p ^ (r & 7);
            gload_lds16(qkv + (size_t)(b * SS + kt * 64 + r) * 1536 + h * 64 + 512 + q * 8,
                        &lK[buf][(size_t)g * 8]);
        }
    };
    auto loadV = [&](int kt, ushort_t* vs) {
        const ushort_t* vsrc = qkv + (size_t)(b * SS + kt * 64 + vkey) * 1536
                               + h * 64 + 1024 + vdg * 32;
        #pragma unroll
        for (int i4 = 0; i4 < 4; i4++)
            *(uint4*)(vs + i4 * 8) = *(const uint4*)(vsrc + i4 * 8);
    };
    auto writeV = [&](const ushort_t* vs, int buf) {
        #pragma unroll
        for (int e = 0; e < 32; e++) {
            int n = vdg * 32 + e;
            lVT[buf][(size_t)(n * 8 + (vk8 ^ (n & 7))) * 8 + vj] = vs[e];
        }
    };

    // prologue: stage tile 0 into buffer 0
    {
        ushort_t v0[32];
        stageK(0, 0);
        loadV(0, v0);
        writeV(v0, 0);
    }
    __syncthreads();

    for (int kt = 0; kt < 16; kt++) {
        const int cur = kt & 1;

        // prefetch tile kt+1: K via async DMA, V into regs (latency hides
        // under this tile's compute; V^T ds_writes land after compute)
        ushort_t vn[32];
        if (kt < 15) {
            stageK(kt + 1, cur ^ 1);
            loadV(kt + 1, vn);
        }

        // QK^T
        facc_t sf[4];
        #pragma unroll
        for (int t = 0; t < 4; t++) sf[t] = (facc_t){0.f, 0.f, 0.f, 0.f};
        #pragma unroll
        for (int ks = 0; ks < 2; ks++) {
            #pragma unroll
            for (int t = 0; t < 4; t++) {
                int row = t * 16 + lane16;
                int q = ks * 4 + quad;
                bfrag_t kf = *(const bfrag_t*)(&lK[cur][((size_t)row * 8 + (q ^ (row & 7))) * 8]);
                sf[t] = __builtin_amdgcn_mfma_f32_16x16x32_bf16(qa[ks], kf, sf[t], 0, 0, 0);
            }
        }

        // online softmax (scores scaled 1/8), exp2-domain, deferred rescale
        float mt_[4];
        #pragma unroll
        for (int r = 0; r < 4; r++)
            mt_[r] = fmaxf(fmaxf(sf[0][r], sf[1][r]), fmaxf(sf[2][r], sf[3][r])) * 0.125f;
        #pragma unroll
        for (int off = 1; off < 16; off <<= 1)
            #pragma unroll
            for (int r = 0; r < 4; r++)
                mt_[r] = fmaxf(mt_[r], __shfl_xor(mt_[r], off));

        bool small = (mt_[0] <= mrow[0] + 8.f) && (mt_[1] <= mrow[1] + 8.f)
                  && (mt_[2] <= mrow[2] + 8.f) && (mt_[3] <= mrow[3] + 8.f);
        if (!__all(small)) {
            #pragma unroll
            for (int r = 0; r < 4; r++) {
                float mn = fmaxf(mrow[r], mt_[r]);
                float al = __builtin_amdgcn_exp2f((mrow[r] - mn) * LOG2E);  // first tile: 0
                mrow[r] = mn;
                lrow[r] *= al;
                O[0][r] *= al; O[1][r] *= al; O[2][r] *= al; O[3][r] *= al;
            }
        }
        float mC[4];
        #pragma unroll
        for (int r = 0; r < 4; r++) mC[r] = mrow[r] * LOG2E;

        float ps[4] = {0.f, 0.f, 0.f, 0.f};
        ushort_t* Pw = lP + w * 1024;
        #pragma unroll
        for (int t = 0; t < 4; t++) {
            int k8 = t * 2 + (lane16 >> 3);
            int j = lane16 & 7;
            #pragma unroll
            for (int r = 0; r < 4; r++) {
                float p = __builtin_amdgcn_exp2f(fmaf(sf[t][r], SC, -mC[r]));
                ps[r] += p;
                int row = quad * 4 + r;
                Pw[(size_t)(row * 8 + (k8 ^ (row & 7))) * 8 + j] = f2bf(p);
            }
        }
        #pragma unroll
        for (int off = 1; off < 16; off <<= 1)
            #pragma unroll
            for (int r = 0; r < 4; r++)
                ps[r] += __shfl_xor(ps[r], off);
        #pragma unroll
        for (int r = 0; r < 4; r++)
            lrow[r] += ps[r];

        // PV (P wave-private: no barrier needed)
        #pragma unroll
        for (int ks = 0; ks < 2; ks++) {
            int q = ks * 4 + quad;
            bfrag_t pf = *(const bfrag_t*)(Pw + ((size_t)lane16 * 8 + (q ^ (lane16 & 7))) * 8);
            #pragma unroll
            for (int t = 0; t < 4; t++) {
                int n = t * 16 + lane16;
                bfrag_t vf = *(const bfrag_t*)(&lVT[cur][((size_t)n * 8 + (q ^ (n & 7))) * 8]);
                O[t] = __builtin_amdgcn_mfma_f32_16x16x32_bf16(pf, vf, O[t], 0, 0, 0);
            }
        }

        // commit prefetched V^T into the other buffer (disjoint from cur)
        if (kt < 15) writeV(vn, cur ^ 1);

        // one barrier per tile: waits K-DMA (vmcnt0) + makes V writes visible
        __syncthreads();
    }

    // epilogue: normalize, store bf16 (flat [b][h][s][d] == ref reshape)
    size_t obase = ((size_t)((b * NH + h) * SS) + qt * 32 + w * 16 + quad * 4) * DH;
    #pragma unroll
    for (int r = 0; r < 4; r++) {
        float inv = 1.f / lrow[r];
        #pragma unroll
        for (int t = 0; t < 4; t++)
            ab[obase + (size_t)r * DH + t * 16 + lane16] = f2bf(O[t][r] * inv);
    }
}

// ---------------------------------------------------------------------------
// LayerNorm(x + delta) * g + b -> outf (f32) and outb (bf16)
// ---------------------------------------------------------------------------
__global__ __launch_bounds__(256) void add_ln(const float* __restrict__ x,
                                              const float* __restrict__ delta,
                                              const float* __restrict__ g,
                                              const float* __restrict__ bparm,
                                              float* __restrict__ outf,
                                              ushort_t* __restrict__ outb) {
    __shared__ float red[2][4];
    int row = blockIdx.x;
    int t = threadIdx.x;
    const float* xr = x + (size_t)row * D_MODEL;
    const float* dr = delta + (size_t)row * D_MODEL;
    float v0 = xr[t] + dr[t];
    float v1 = xr[t + 256] + dr[t + 256];
    float s = v0 + v1;
    float ss = v0 * v0 + v1 * v1;
    #pragma unroll
    for (int off = 1; off < 64; off <<= 1) {
        s  += __shfl_xor(s, off);
        ss += __shfl_xor(ss, off);
    }
    int lane = t & 63, wid = t >> 6;
    if (lane == 0) { red[0][wid] = s; red[1][wid] = ss; }
    __syncthreads();
    s  = red[0][0] + red[0][1] + red[0][2] + red[0][3];
    ss = red[1][0] + red[1][1] + red[1][2] + red[1][3];
    float mean = s * (1.f / D_MODEL);
    float var = ss * (1.f / D_MODEL) - mean * mean;
    float rinv = rsqrtf(var + 1e-5f);
    float o0 = (v0 - mean) * rinv * g[t]       + bparm[t];
    float o1 = (v1 - mean) * rinv * g[t + 256] + bparm[t + 256];
    float* orow = outf + (size_t)row * D_MODEL;
    orow[t] = o0; orow[t + 256] = o1;
    ushort_t* brow = outb + (size_t)row * D_MODEL;
    brow[t] = f2bf(o0); brow[t + 256] = f2bf(o1);
}

// ---------------------------------------------------------------------------
extern "C" void kernel_launch(void* const* d_in, const int* in_sizes, int n_in,
                              void* d_out, int out_size, void* d_ws, size_t ws_size,
                              hipStream_t stream) {
    const int* tokens = (const int*)d_in[0];
    const float* emb = (const float*)d_in[1];
    const float* Wq = (const float*)d_in[2];  const float* bq = (const float*)d_in[3];
    const float* Wk = (const float*)d_in[4];  const float* bk = (const float*)d_in[5];
    const float* Wv = (const float*)d_in[6];  const float* bv = (const float*)d_in[7];
    const float* Wo = (const float*)d_in[8];  const float* bo = (const float*)d_in[9];
    const float* W1 = (const float*)d_in[10]; const float* b1 = (const float*)d_in[11];
    const float* W2 = (const float*)d_in[12]; const float* b2 = (const float*)d_in[13];
    const float* lng = (const float*)d_in[14]; const float* lnb = (const float*)d_in[15];

    // ws layout (bytes) — total 44,077,056
    char* base = (char*)d_ws;
    ushort_t* wlay = (ushort_t*)(base);                 //  6,291,456  rotating Wt
    float*    bqkv = (float*)   (base + 6291456);       //     36,864
    float*    x    = (float*)   (base + 6328320);       //  8,388,608
    ushort_t* xbf  = (ushort_t*)(base + 14716928);      //  4,194,304
    float*    tmp  = (float*)   (base + 18911232);      //  8,388,608
    ushort_t* qkv  = (ushort_t*)(base + 27299840);      // 12,582,912
    ushort_t* ab   = (ushort_t*)(base + 39882752);      //  4,194,304
    ushort_t* mid  = qkv;  // [4096][2048] bf16, aliases qkv+ab (dead by FFN)

    ushort_t* wqkv_t = wlay;             // [1536][512]
    ushort_t* wo_t   = wlay + 786432;    // [512][512]
    ushort_t* w1_t   = wlay + 1048576;   // [2048][512]
    ushort_t* w2_t   = wlay + 2097152;   // [512][2048]

    concat_bias<<<NL, 256, 0, stream>>>(bq, bk, bv, bqkv);
    embed_pe<<<ROWS, 256, 0, stream>>>(tokens, emb, x, xbf);

    for (int l = 0; l < NL; l++) {
        prep_weights<<<dim3(64, 64, 6), 256, 0, stream>>>(Wq, Wk, Wv, Wo, W1, W2, l, wlay);

        gemm_mfma<<<dim3(12, 32), 256, 0, stream>>>(xbf, wqkv_t, bqkv + l * 1536,
                                                    nullptr, qkv, 1536, 512, 0);
        attn_mfma<<<dim3(32, NH, BB), 128, 0, stream>>>(qkv, ab);

        gemm_mfma64<<<dim3(8, 64), 256, 0, stream>>>(ab, wo_t, bo + l * D_MODEL,
                                                     tmp, nullptr, 512, 512, 0);
        add_ln<<<ROWS, 256, 0, stream>>>(x, tmp, lng + l * D_MODEL, lnb + l * D_MODEL,
                                         x, xbf);

        gemm_mfma<<<dim3(16, 32), 256, 0, stream>>>(xbf, w1_t, b1 + l * DFF,
                                                    nullptr, mid, 2048, 512, 1);
        gemm_mfma64<<<dim3(8, 64), 256, 0, stream>>>(mid, w2_t, b2 + l * D_MODEL,
                                                     tmp, nullptr, 512, 2048, 0);
        float* lnout = (l == NL - 1) ? (float*)d_out : x;
        add_ln<<<ROWS, 256, 0, stream>>>(x, tmp, lng + l * D_MODEL, lnb + l * D_MODEL,
                                         lnout, xbf);
    }
}